// Round 19
// baseline (287.023 us; speedup 1.0000x reference)
//
#include <hip/hip_runtime.h>
#include <hip/hip_bf16.h>
#include <math.h>

constexpr int N_NODES = 50000;
constexpr int HD = 64;
constexpr int NBKT = (N_NODES + 255) / 256;   // 196 buckets of 256 nodes

typedef float floatx2 __attribute__((ext_vector_type(2)));

__device__ __forceinline__ float bf2f(unsigned short u) {
    return __uint_as_float((unsigned)u << 16);
}
__device__ __forceinline__ unsigned short f2bf(float f) {
    __hip_bfloat16 b = __float2bfloat16(f);
    return *(unsigned short*)&b;
}
__device__ __forceinline__ unsigned pack_fp8x4(float a, float b, float c, float d) {
    unsigned p = __builtin_amdgcn_cvt_pk_fp8_f32(a, b, 0u, false);
    return __builtin_amdgcn_cvt_pk_fp8_f32(c, d, p, true);
}
// dot of 16 fp8 pairs held in two uint4s
__device__ __forceinline__ float dot16_fp8(uint4 u, uint4 d) {
    const unsigned uu[4] = {u.x, u.y, u.z, u.w};
    const unsigned dd[4] = {d.x, d.y, d.z, d.w};
    float s = 0.f;
#pragma unroll
    for (int q = 0; q < 4; ++q) {
        floatx2 ua = __builtin_amdgcn_cvt_pk_f32_fp8(uu[q], false);
        floatx2 ub = __builtin_amdgcn_cvt_pk_f32_fp8(uu[q], true);
        floatx2 da = __builtin_amdgcn_cvt_pk_f32_fp8(dd[q], false);
        floatx2 db = __builtin_amdgcn_cvt_pk_f32_fp8(dd[q], true);
        s = fmaf(ua[0], da[0], s);
        s = fmaf(ua[1], da[1], s);
        s = fmaf(ub[0], db[0], s);
        s = fmaf(ub[1], db[1], s);
    }
    return s;
}

// ---------- A: bucket histogram (LDS-staged) ----------
__global__ __launch_bounds__(256) void bhist_kernel(const int* __restrict__ dst,
                                                    int* __restrict__ bcnt, int E) {
    __shared__ int lh[256];
    const int t = threadIdx.x;
    lh[t] = 0;
    __syncthreads();
    const int beg = blockIdx.x * 2048;
    const int end = min(beg + 2048, E);
    for (int i = beg + t; i < end; i += 256)
        atomicAdd(&lh[dst[i] >> 8], 1);
    __syncthreads();
    if (t < NBKT && lh[t]) atomicAdd(&bcnt[t], lh[t]);
}

// ---------- B: scan bucket counts -> bbase, init gcur ----------
__global__ __launch_bounds__(256) void bscan_kernel(const int* __restrict__ bcnt,
                                                    int* __restrict__ bbase,
                                                    int* __restrict__ gcur) {
    const int t = threadIdx.x;
    const int v = (t < NBKT) ? bcnt[t] : 0;
    const int lane = t & 63, wid = t >> 6;
    int incl = v;
#pragma unroll
    for (int o = 1; o <= 32; o <<= 1) {
        int u = __shfl_up(incl, o);
        if (lane >= o) incl += u;
    }
    __shared__ int wt[4];
    if (lane == 63) wt[wid] = incl;
    __syncthreads();
    int base = 0;
    for (int w = 0; w < wid; ++w) base += wt[w];
    const int excl = base + incl - v;
    if (t < NBKT) { bbase[t] = excl; gcur[t] = excl; }
    if (t == NBKT - 1) bbase[NBKT] = excl + v;
}

// ---------- C: partition edges into bucket-grouped pk ----------
__global__ __launch_bounds__(256) void partition_kernel(const int* __restrict__ src,
                                                        const int* __restrict__ dst,
                                                        int* __restrict__ gcur,
                                                        unsigned* __restrict__ pk, int E) {
    __shared__ unsigned epk[8192];
    __shared__ int lh[NBKT], lbase[NBKT], lcur[NBKT];
    const int t = threadIdx.x;
    for (int i = t; i < NBKT; i += 256) { lh[i] = 0; lcur[i] = 0; }
    __syncthreads();
    const int beg = blockIdx.x * 8192;
    const int end = min(beg + 8192, E);
    for (int i = beg + t; i < end; i += 256) {
        const int s = src[i], d = dst[i];
        const int bkt = d >> 8;
        epk[i - beg] = ((unsigned)bkt << 24) | ((unsigned)(d & 255) << 16) | (unsigned)s;
        atomicAdd(&lh[bkt], 1);
    }
    __syncthreads();
    for (int i = t; i < NBKT; i += 256)
        if (lh[i]) lbase[i] = atomicAdd(&gcur[i], lh[i]);
    __syncthreads();
    for (int i = beg + t; i < end; i += 256) {
        const unsigned p = epk[i - beg];
        const int bkt = p >> 24;
        const int r = atomicAdd(&lcur[bkt], 1);
        pk[lbase[bkt] + r] = p;
    }
}

// ---------- D: per-bucket counting sort -> csr, off, dis ----------
__global__ __launch_bounds__(256) void bsort_kernel(const unsigned* __restrict__ pk,
                                                    const int* __restrict__ bbase,
                                                    int* __restrict__ off,
                                                    float* __restrict__ dis,
                                                    int* __restrict__ csr, int E, int N) {
    __shared__ int ncnt[256], nbs[256], ncur[256];
    __shared__ int wt[4];
    const int t = threadIdx.x;
    const int bkt = blockIdx.x;
    const int gb = bbase[bkt], ge = bbase[bkt + 1];
    ncnt[t] = 0; ncur[t] = 0;
    __syncthreads();
    for (int i = gb + t; i < ge; i += 256)
        atomicAdd(&ncnt[(pk[i] >> 16) & 255], 1);
    __syncthreads();
    const int v = ncnt[t];
    const int lane = t & 63, wid = t >> 6;
    int incl = v;
#pragma unroll
    for (int o = 1; o <= 32; o <<= 1) {
        int u = __shfl_up(incl, o);
        if (lane >= o) incl += u;
    }
    if (lane == 63) wt[wid] = incl;
    __syncthreads();
    int base = 0;
    for (int w = 0; w < wid; ++w) base += wt[w];
    nbs[t] = base + incl - v;
    const int n = bkt * 256 + t;
    if (n < N) {
        off[n] = gb + nbs[t];
        dis[n] = rsqrtf((float)v + 1.0f);
        if (n == N - 1) off[N] = E;
    }
    __syncthreads();
    for (int i = gb + t; i < ge; i += 256) {
        const unsigned p = pk[i];
        const int dl = (p >> 16) & 255;
        const int r = atomicAdd(&ncur[dl], 1);
        csr[gb + nbs[dl] + r] = (int)(p & 0xFFFFu);
    }
}

// ---------- GEMM K=128 (fp32 in): emits ONLY pre-scaled fp8 hs = (x@W)*dis ----------
__global__ __launch_bounds__(256) void gemm128_kernel(const float* __restrict__ in_,
                                                      const float* __restrict__ W,
                                                      const float* __restrict__ dis,
                                                      unsigned* __restrict__ out8, int N) {
    constexpr int K = 128;
    __shared__ float xs[64][68];
    __shared__ float Wl[64][64];
    const int t = threadIdx.x;
    const int row0 = blockIdx.x * 64;
    const int cq = t & 15, rq = t >> 4;
    float acc[4][4] = {{0.f}};
    for (int kc = 0; kc < K; kc += 64) {
#pragma unroll
        for (int it = 0; it < 4; ++it) {
            const int idx = it * 256 + t;
            const int r = idx >> 4, c4 = idx & 15;
            const int rr = min(row0 + r, N - 1);
            *(float4*)(&xs[r][c4 * 4]) = *(const float4*)(in_ + (size_t)rr * K + kc + c4 * 4);
            *(float4*)(&Wl[r][c4 * 4]) = *(const float4*)(W + (size_t)(kc + r) * HD + c4 * 4);
        }
        __syncthreads();
#pragma unroll
        for (int k4 = 0; k4 < 16; ++k4) {
            float a[4][4], b[4][4];
#pragma unroll
            for (int i = 0; i < 4; ++i)
                *(float4*)a[i] = *(const float4*)(&xs[rq * 4 + i][k4 * 4]);
#pragma unroll
            for (int kk = 0; kk < 4; ++kk)
                *(float4*)b[kk] = *(const float4*)(&Wl[k4 * 4 + kk][cq * 4]);
#pragma unroll
            for (int kk = 0; kk < 4; ++kk)
#pragma unroll
                for (int i = 0; i < 4; ++i)
#pragma unroll
                    for (int j = 0; j < 4; ++j)
                        acc[i][j] = fmaf(a[i][kk], b[kk][j], acc[i][j]);
        }
        __syncthreads();
    }
#pragma unroll
    for (int i = 0; i < 4; ++i) {
        const int r = row0 + rq * 4 + i;
        if (r < N) {
            const float dr = dis[r];
            out8[(size_t)r * 16 + cq] =
                pack_fp8x4(acc[i][0] * dr, acc[i][1] * dr, acc[i][2] * dr, acc[i][3] * dr);
        }
    }
}

// ---------- GEMM K=64 (bf16 in): emits ONLY pre-scaled fp8 hs ----------
__global__ __launch_bounds__(256) void gemm64_kernel(const unsigned short* __restrict__ in16,
                                                     const float* __restrict__ W,
                                                     const float* __restrict__ dis,
                                                     unsigned* __restrict__ out8, int N) {
    constexpr int K = 64;
    __shared__ float xs[64][68];
    __shared__ float Wl[64][64];
    const int t = threadIdx.x;
    const int row0 = blockIdx.x * 64;
    const int cq = t & 15, rq = t >> 4;
    float acc[4][4] = {{0.f}};
    {
#pragma unroll
        for (int it = 0; it < 4; ++it) {
            const int idx = it * 256 + t;
            const int r = idx >> 4, c4 = idx & 15;
            const int rr = min(row0 + r, N - 1);
            const ushort4 v = *(const ushort4*)(in16 + (size_t)rr * K + c4 * 4);
            *(float4*)(&xs[r][c4 * 4]) = make_float4(bf2f(v.x), bf2f(v.y), bf2f(v.z), bf2f(v.w));
            *(float4*)(&Wl[r][c4 * 4]) = *(const float4*)(W + (size_t)r * HD + c4 * 4);
        }
        __syncthreads();
#pragma unroll
        for (int k4 = 0; k4 < 16; ++k4) {
            float a[4][4], b[4][4];
#pragma unroll
            for (int i = 0; i < 4; ++i)
                *(float4*)a[i] = *(const float4*)(&xs[rq * 4 + i][k4 * 4]);
#pragma unroll
            for (int kk = 0; kk < 4; ++kk)
                *(float4*)b[kk] = *(const float4*)(&Wl[k4 * 4 + kk][cq * 4]);
#pragma unroll
            for (int kk = 0; kk < 4; ++kk)
#pragma unroll
                for (int i = 0; i < 4; ++i)
#pragma unroll
                    for (int j = 0; j < 4; ++j)
                        acc[i][j] = fmaf(a[i][kk], b[kk][j], acc[i][j]);
        }
    }
#pragma unroll
    for (int i = 0; i < 4; ++i) {
        const int r = row0 + rq * 4 + i;
        if (r < N) {
            const float dr = dis[r];
            out8[(size_t)r * 16 + cq] =
                pack_fp8x4(acc[i][0] * dr, acc[i][1] * dr, acc[i][2] * dr, acc[i][3] * dr);
        }
    }
}

// ---------- fused aggregation (pre-scaled hs): out = relu(dn*(sum_e hs[src] + hs[n]) + b) ----------
// lane = (g = lane>>3 edge slot, p = lane&7 h-octet). Sentinel zero row N for lanes >= degree.
// FINAL variant additionally emits u8/d8 (folds uprep).
template <bool FINAL>
__global__ __launch_bounds__(256) void agg_kernel(const int* __restrict__ csr,
                                                  const int* __restrict__ off,
                                                  const float* __restrict__ dis,
                                                  const unsigned* __restrict__ hs,
                                                  const float* __restrict__ b,
                                                  unsigned short* __restrict__ z16out,
                                                  const unsigned short* __restrict__ zall,
                                                  const float* __restrict__ Wp,
                                                  unsigned* __restrict__ u8,
                                                  unsigned* __restrict__ d8, int N) {
    const int lane = threadIdx.x & 63;
    const int wid  = threadIdx.x >> 6;
    const int n = blockIdx.x * 4 + wid;
    if (n >= N) return;
    const int beg = off[n];
    const int c = min(off[n + 1] - beg, 64);
    int s_l = N;                                 // sentinel zero row
    if (lane < c) s_l = csr[beg + lane];
    const float dn = dis[n];
    const int g = lane >> 3;
    const int p = lane & 7;
    float a[8];
#pragma unroll
    for (int j = 0; j < 8; ++j) a[j] = 0.f;
    int sE = __shfl(s_l, g);
    uint2 hv = *(const uint2*)(hs + (size_t)sE * 16 + p * 2);
    for (int e = 8; e < c; e += 8) {
        const int sN = __shfl(s_l, e + g);
        const uint2 nv = *(const uint2*)(hs + (size_t)sN * 16 + p * 2);
        floatx2 f01 = __builtin_amdgcn_cvt_pk_f32_fp8(hv.x, false);
        floatx2 f23 = __builtin_amdgcn_cvt_pk_f32_fp8(hv.x, true);
        floatx2 f45 = __builtin_amdgcn_cvt_pk_f32_fp8(hv.y, false);
        floatx2 f67 = __builtin_amdgcn_cvt_pk_f32_fp8(hv.y, true);
        a[0] += f01[0]; a[1] += f01[1]; a[2] += f23[0]; a[3] += f23[1];
        a[4] += f45[0]; a[5] += f45[1]; a[6] += f67[0]; a[7] += f67[1];
        hv = nv;
    }
    {
        floatx2 f01 = __builtin_amdgcn_cvt_pk_f32_fp8(hv.x, false);
        floatx2 f23 = __builtin_amdgcn_cvt_pk_f32_fp8(hv.x, true);
        floatx2 f45 = __builtin_amdgcn_cvt_pk_f32_fp8(hv.y, false);
        floatx2 f67 = __builtin_amdgcn_cvt_pk_f32_fp8(hv.y, true);
        a[0] += f01[0]; a[1] += f01[1]; a[2] += f23[0]; a[3] += f23[1];
        a[4] += f45[0]; a[5] += f45[1]; a[6] += f67[0]; a[7] += f67[1];
    }
#pragma unroll
    for (int st = 8; st <= 32; st <<= 1)
#pragma unroll
        for (int j = 0; j < 8; ++j) a[j] += __shfl_xor(a[j], st);
    if (g == 0) {
        const uint2 sv = *(const uint2*)(hs + (size_t)n * 16 + p * 2);
        floatx2 s01 = __builtin_amdgcn_cvt_pk_f32_fp8(sv.x, false);
        floatx2 s23 = __builtin_amdgcn_cvt_pk_f32_fp8(sv.x, true);
        floatx2 s45 = __builtin_amdgcn_cvt_pk_f32_fp8(sv.y, false);
        floatx2 s67 = __builtin_amdgcn_cvt_pk_f32_fp8(sv.y, true);
        a[0] += s01[0]; a[1] += s01[1]; a[2] += s23[0]; a[3] += s23[1];
        a[4] += s45[0]; a[5] += s45[1]; a[6] += s67[0]; a[7] += s67[1];
        const float4 b0 = *(const float4*)(b + p * 8);
        const float4 b1 = *(const float4*)(b + p * 8 + 4);
        const float bb[8] = {b0.x, b0.y, b0.z, b0.w, b1.x, b1.y, b1.z, b1.w};
        unsigned short z3b[8];
#pragma unroll
        for (int j = 0; j < 8; ++j) {
            const float v = fmaxf(fmaf(a[j], dn, bb[j]), 0.f);
            z3b[j] = f2bf(v);
        }
        unsigned short* zp = z16out + (size_t)n * HD + p * 8;
        *(ushort4*)zp = *(ushort4*)z3b;
        *(ushort4*)(zp + 4) = *(ushort4*)(z3b + 4);
        if constexpr (FINAL) {
            const size_t NH = (size_t)N_NODES * HD;
            const unsigned short* l0 = zall + 0 * NH + (size_t)n * HD + p * 8;
            const unsigned short* l1 = zall + 1 * NH + (size_t)n * HD + p * 8;
            const unsigned short* l2 = zall + 2 * NH + (size_t)n * HD + p * 8;
            unsigned short L0[8], L1[8], L2[8];
            *(ushort4*)L0 = *(const ushort4*)l0; *(ushort4*)(L0 + 4) = *(const ushort4*)(l0 + 4);
            *(ushort4*)L1 = *(const ushort4*)l1; *(ushort4*)(L1 + 4) = *(const ushort4*)(l1 + 4);
            *(ushort4*)L2 = *(const ushort4*)l2; *(ushort4*)(L2 + 4) = *(const ushort4*)(l2 + 4);
            float wpc[16];
#pragma unroll
            for (int m = 0; m < 16; ++m) wpc[m] = Wp[m];
            unsigned uo[8], dvo[8];
#pragma unroll
            for (int j = 0; j < 8; ++j) {
                const float v0 = bf2f(L0[j]), v1 = bf2f(L1[j]);
                const float v2 = bf2f(L2[j]), v3 = bf2f(z3b[j]);
                dvo[j] = pack_fp8x4(v0, v1, v2, v3);
                const float u0v = v0 * wpc[0] + v1 * wpc[4] + v2 * wpc[8]  + v3 * wpc[12];
                const float u1v = v0 * wpc[1] + v1 * wpc[5] + v2 * wpc[9]  + v3 * wpc[13];
                const float u2v = v0 * wpc[2] + v1 * wpc[6] + v2 * wpc[10] + v3 * wpc[14];
                const float u3v = v0 * wpc[3] + v1 * wpc[7] + v2 * wpc[11] + v3 * wpc[15];
                uo[j] = pack_fp8x4(u0v, u1v, u2v, u3v);
            }
            unsigned* up = u8 + (size_t)n * HD + p * 8;
            unsigned* dp = d8 + (size_t)n * HD + p * 8;
            *(uint4*)up = *(uint4*)uo;  *(uint4*)(up + 4) = *(uint4*)(uo + 4);
            *(uint4*)dp = *(uint4*)dvo; *(uint4*)(dp + 4) = *(uint4*)(dvo + 4);
        }
    }
}

// ---------- link prediction + BCE loss: 16-lane groups, 8 edges / wave-iter ----------
__global__ __launch_bounds__(256) void linkpred_kernel(const unsigned* __restrict__ u8,
                                                       const unsigned* __restrict__ d8,
                                                       const int* __restrict__ pos,
                                                       const int* __restrict__ neg,
                                                       const float* __restrict__ bp,
                                                       double* __restrict__ acc, int EP) {
    const int lane = threadIdx.x & 63;
    const int wid  = threadIdx.x >> 6;
    const int grp  = lane >> 4;
    const int p    = lane & 15;
    const float bpv = bp[0];
    int gw = blockIdx.x * 4 + wid;
    const int nw = gridDim.x * 4;
    const int nchunks = (2 * EP) >> 3;
    float lsum = 0.f;
    for (int c0 = gw; c0 < nchunks; c0 += nw) {
        const int c = __builtin_amdgcn_readfirstlane(c0);
        const int i0 = c << 3;
        const bool is_pos = i0 < EP;
        const int* __restrict__ eptr = is_pos ? pos : neg;
        const int jj0 = is_pos ? i0 : i0 - EP;
        int idx = 0;
        if (lane < 16)
            idx = (lane < 8) ? eptr[jj0 + lane] : eptr[EP + jj0 + lane - 8];
        const int e0a = __shfl(idx, grp),     e1a = __shfl(idx, 8 + grp);
        const int e0b = __shfl(idx, 4 + grp), e1b = __shfl(idx, 12 + grp);
        const uint4 ua = *(const uint4*)(u8 + (size_t)e0a * HD + p * 4);
        const uint4 da = *(const uint4*)(d8 + (size_t)e1a * HD + p * 4);
        const uint4 ub = *(const uint4*)(u8 + (size_t)e0b * HD + p * 4);
        const uint4 db = *(const uint4*)(d8 + (size_t)e1b * HD + p * 4);
        float tA = dot16_fp8(ua, da);
        float tB = dot16_fp8(ub, db);
#pragma unroll
        for (int st = 1; st <= 8; st <<= 1) {
            tA += __shfl_xor(tA, st);
            tB += __shfl_xor(tB, st);
        }
        const float ga = __shfl(tA, (lane & 3) * 16);
        const float gb = __shfl(tB, (lane & 3) * 16);
        const float tt = (lane < 4) ? ga : gb;
        if (lane < 8) {
            float logit  = tt + bpv;
            float target = (i0 + lane == EP) ? 1.f : 0.f;
            lsum += fmaxf(logit, 0.f) - logit * target + log1pf(expf(-fabsf(logit)));
        }
    }
#pragma unroll
    for (int o = 32; o >= 1; o >>= 1) lsum += __shfl_xor(lsum, o);
    __shared__ float wsum[4];
    if (lane == 0) wsum[wid] = lsum;
    __syncthreads();
    if (threadIdx.x == 0) {
        double bs = (double)wsum[0] + (double)wsum[1] + (double)wsum[2] + (double)wsum[3];
        atomicAdd(acc, bs);
    }
}

__global__ void loss_final(const double* __restrict__ acc, float* __restrict__ out, int denom) {
    out[0] = (float)(acc[0] / (double)denom);
}

extern "C" void kernel_launch(void* const* d_in, const int* in_sizes, int n_in,
                              void* d_out, int out_size, void* d_ws, size_t ws_size,
                              hipStream_t stream) {
    const float* x   = (const float*)d_in[0];
    const int*   ei  = (const int*)d_in[1];
    const int*   pos = (const int*)d_in[2];
    const int*   neg = (const int*)d_in[3];
    const float* W0  = (const float*)d_in[4];
    const float* b0  = (const float*)d_in[5];
    const float* Wh  = (const float*)d_in[6];
    const float* bh  = (const float*)d_in[7];
    const float* Wp  = (const float*)d_in[8];
    const float* bp  = (const float*)d_in[9];
    const int E  = in_sizes[1] / 2;   // 800000
    const int EP = in_sizes[2] / 2;   // 100000
    const int N  = N_NODES;
    const size_t NH = (size_t)N * HD;

    // ---- workspace layout (256B aligned) ----
    char* ws = (char*)d_ws;
    size_t off_b = 0;
    auto alloc = [&](size_t bytes) { char* p = ws + off_b; off_b = (off_b + bytes + 255) & ~(size_t)255; return p; };
    unsigned*       hs  = (unsigned*)alloc((size_t)(N + 1) * 16 * sizeof(unsigned)); // 3.2 MB (+sentinel row N)
    unsigned short* z16 = (unsigned short*)alloc(4 * NH * sizeof(unsigned short));   // 25.6 MB
    unsigned*       u8  = (unsigned*)alloc(NH * sizeof(unsigned));                   // 12.8 MB
    unsigned*       d8  = (unsigned*)alloc(NH * sizeof(unsigned));                   // 12.8 MB
    float* dis = (float*)alloc((size_t)N * sizeof(float));                           // 200 KB
    int*   off = (int*)alloc((size_t)(N + 1) * sizeof(int));                         // 200 KB
    int*   csr = (int*)alloc((size_t)E * sizeof(int));                               // 3.2 MB
    unsigned* pk = (unsigned*)alloc((size_t)E * sizeof(unsigned));                   // 3.2 MB
    int*   bbase = (int*)alloc((size_t)(NBKT + 1) * sizeof(int));
    int*   gcur  = (int*)alloc((size_t)NBKT * sizeof(int));
    char*  zbase = ws + off_b;
    int*   bcnt = (int*)alloc((size_t)NBKT * sizeof(int));
    double* acc = (double*)alloc(sizeof(double));
    size_t zero_bytes = (size_t)((char*)acc - zbase) + sizeof(double);

    hipMemsetAsync(zbase, 0, zero_bytes, stream);
    hipMemsetAsync(hs + (size_t)N * 16, 0, 16 * sizeof(unsigned), stream);  // sentinel row

    const int* src = ei;
    const int* dst = ei + E;

    // CSR build: bucket hist -> scan -> partition -> per-bucket sort (+off, dis)
    bhist_kernel<<<(E + 2047) / 2048, 256, 0, stream>>>(dst, bcnt, E);
    bscan_kernel<<<1, 256, 0, stream>>>(bcnt, bbase, gcur);
    partition_kernel<<<(E + 8191) / 8192, 256, 0, stream>>>(src, dst, gcur, pk, E);
    bsort_kernel<<<NBKT, 256, 0, stream>>>(pk, bbase, off, dis, csr, E, N);

    const int gemm_blocks = (N + 63) / 64;
    const int agg_blocks  = (N + 3) / 4;

    // layer 0 (gemm needs dis -> after bsort)
    gemm128_kernel<<<gemm_blocks, 256, 0, stream>>>(x, W0, dis, hs, N);
    agg_kernel<false><<<agg_blocks, 256, 0, stream>>>(csr, off, dis, hs, b0,
                                                      z16, z16, Wp, u8, d8, N);

    // layers 1..3 (layer 3 agg folds uprep)
    for (int l = 1; l < 4; ++l) {
        unsigned short* zprev = z16 + (size_t)(l - 1) * NH;
        unsigned short* zcur  = z16 + (size_t)l * NH;
        gemm64_kernel<<<gemm_blocks, 256, 0, stream>>>(zprev, Wh + (size_t)(l - 1) * HD * HD,
                                                       dis, hs, N);
        if (l < 3) {
            agg_kernel<false><<<agg_blocks, 256, 0, stream>>>(csr, off, dis, hs,
                                                              bh + (size_t)(l - 1) * HD,
                                                              zcur, z16, Wp, u8, d8, N);
        } else {
            agg_kernel<true><<<agg_blocks, 256, 0, stream>>>(csr, off, dis, hs,
                                                             bh + (size_t)(l - 1) * HD,
                                                             zcur, z16, Wp, u8, d8, N);
        }
    }

    // link prediction + loss
    linkpred_kernel<<<2048, 256, 0, stream>>>(u8, d8, pos, neg, bp, acc, EP);
    loss_final<<<1, 1, 0, stream>>>(acc, (float*)d_out, 2 * EP);
}

// Round 20
// 275.993 us; speedup vs baseline: 1.0400x; 1.0400x over previous
//
#include <hip/hip_runtime.h>
#include <hip/hip_bf16.h>
#include <math.h>

constexpr int N_NODES = 50000;
constexpr int HD = 64;
constexpr int NBKT = (N_NODES + 255) / 256;   // 196 buckets of 256 nodes

typedef float floatx2 __attribute__((ext_vector_type(2)));

__device__ __forceinline__ float bf2f(unsigned short u) {
    return __uint_as_float((unsigned)u << 16);
}
__device__ __forceinline__ unsigned short f2bf(float f) {
    __hip_bfloat16 b = __float2bfloat16(f);
    return *(unsigned short*)&b;
}
__device__ __forceinline__ unsigned pack_fp8x4(float a, float b, float c, float d) {
    unsigned p = __builtin_amdgcn_cvt_pk_fp8_f32(a, b, 0u, false);
    return __builtin_amdgcn_cvt_pk_fp8_f32(c, d, p, true);
}
// dot of 16 fp8 pairs held in two uint4s
__device__ __forceinline__ float dot16_fp8(uint4 u, uint4 d) {
    const unsigned uu[4] = {u.x, u.y, u.z, u.w};
    const unsigned dd[4] = {d.x, d.y, d.z, d.w};
    float s = 0.f;
#pragma unroll
    for (int q = 0; q < 4; ++q) {
        floatx2 ua = __builtin_amdgcn_cvt_pk_f32_fp8(uu[q], false);
        floatx2 ub = __builtin_amdgcn_cvt_pk_f32_fp8(uu[q], true);
        floatx2 da = __builtin_amdgcn_cvt_pk_f32_fp8(dd[q], false);
        floatx2 db = __builtin_amdgcn_cvt_pk_f32_fp8(dd[q], true);
        s = fmaf(ua[0], da[0], s);
        s = fmaf(ua[1], da[1], s);
        s = fmaf(ub[0], db[0], s);
        s = fmaf(ub[1], db[1], s);
    }
    return s;
}

// ---------- fused: gemm<128> (blocks < nGemm) + bucket histogram (blocks >= nGemm) ----------
__global__ __launch_bounds__(256) void gemm128_bhist_kernel(
        const float* __restrict__ in_, const float* __restrict__ W,
        unsigned short* __restrict__ out16, unsigned* __restrict__ out8,
        const int* __restrict__ dst, int* __restrict__ bcnt,
        int N, int E, int nGemm) {
    __shared__ float xs[64][68];
    __shared__ float Wl[64][64];
    const int t = threadIdx.x;
    if ((int)blockIdx.x >= nGemm) {
        // --- bhist path (LDS aliased onto xs) ---
        int* lh = (int*)&xs[0][0];
        lh[t] = 0;
        __syncthreads();
        const int beg = ((int)blockIdx.x - nGemm) * 2048;
        const int end = min(beg + 2048, E);
        for (int i = beg + t; i < end; i += 256)
            atomicAdd(&lh[dst[i] >> 8], 1);
        __syncthreads();
        if (t < NBKT && lh[t]) atomicAdd(&bcnt[t], lh[t]);
        return;
    }
    // --- gemm path, K=128, fp32 input ---
    constexpr int K = 128;
    const int row0 = blockIdx.x * 64;
    const int cq = t & 15, rq = t >> 4;
    float acc[4][4] = {{0.f}};
    for (int kc = 0; kc < K; kc += 64) {
#pragma unroll
        for (int it = 0; it < 4; ++it) {
            const int idx = it * 256 + t;
            const int r = idx >> 4, c4 = idx & 15;
            const int rr = min(row0 + r, N - 1);
            *(float4*)(&xs[r][c4 * 4]) = *(const float4*)(in_ + (size_t)rr * K + kc + c4 * 4);
            *(float4*)(&Wl[r][c4 * 4]) = *(const float4*)(W + (size_t)(kc + r) * HD + c4 * 4);
        }
        __syncthreads();
#pragma unroll
        for (int k4 = 0; k4 < 16; ++k4) {
            float a[4][4], b[4][4];
#pragma unroll
            for (int i = 0; i < 4; ++i)
                *(float4*)a[i] = *(const float4*)(&xs[rq * 4 + i][k4 * 4]);
#pragma unroll
            for (int kk = 0; kk < 4; ++kk)
                *(float4*)b[kk] = *(const float4*)(&Wl[k4 * 4 + kk][cq * 4]);
#pragma unroll
            for (int kk = 0; kk < 4; ++kk)
#pragma unroll
                for (int i = 0; i < 4; ++i)
#pragma unroll
                    for (int j = 0; j < 4; ++j)
                        acc[i][j] = fmaf(a[i][kk], b[kk][j], acc[i][j]);
        }
        __syncthreads();
    }
#pragma unroll
    for (int i = 0; i < 4; ++i) {
        const int r = row0 + rq * 4 + i;
        if (r < N) {
            ushort4 o;
            o.x = f2bf(acc[i][0]); o.y = f2bf(acc[i][1]);
            o.z = f2bf(acc[i][2]); o.w = f2bf(acc[i][3]);
            *(ushort4*)(out16 + (size_t)r * HD + cq * 4) = o;
            out8[(size_t)r * 16 + cq] = pack_fp8x4(acc[i][0], acc[i][1], acc[i][2], acc[i][3]);
        }
    }
}

// ---------- B: scan bucket counts -> bbase, init gcur ----------
__global__ __launch_bounds__(256) void bscan_kernel(const int* __restrict__ bcnt,
                                                    int* __restrict__ bbase,
                                                    int* __restrict__ gcur) {
    const int t = threadIdx.x;
    const int v = (t < NBKT) ? bcnt[t] : 0;
    const int lane = t & 63, wid = t >> 6;
    int incl = v;
#pragma unroll
    for (int o = 1; o <= 32; o <<= 1) {
        int u = __shfl_up(incl, o);
        if (lane >= o) incl += u;
    }
    __shared__ int wt[4];
    if (lane == 63) wt[wid] = incl;
    __syncthreads();
    int base = 0;
    for (int w = 0; w < wid; ++w) base += wt[w];
    const int excl = base + incl - v;
    if (t < NBKT) { bbase[t] = excl; gcur[t] = excl; }
    if (t == NBKT - 1) bbase[NBKT] = excl + v;
}

// ---------- C: partition edges into bucket-grouped pk ----------
__global__ __launch_bounds__(256) void partition_kernel(const int* __restrict__ src,
                                                        const int* __restrict__ dst,
                                                        int* __restrict__ gcur,
                                                        unsigned* __restrict__ pk, int E) {
    __shared__ unsigned epk[8192];
    __shared__ int lh[NBKT], lbase[NBKT], lcur[NBKT];
    const int t = threadIdx.x;
    for (int i = t; i < NBKT; i += 256) { lh[i] = 0; lcur[i] = 0; }
    __syncthreads();
    const int beg = blockIdx.x * 8192;
    const int end = min(beg + 8192, E);
    for (int i = beg + t; i < end; i += 256) {
        const int s = src[i], d = dst[i];
        const int bkt = d >> 8;
        epk[i - beg] = ((unsigned)bkt << 24) | ((unsigned)(d & 255) << 16) | (unsigned)s;
        atomicAdd(&lh[bkt], 1);
    }
    __syncthreads();
    for (int i = t; i < NBKT; i += 256)
        if (lh[i]) lbase[i] = atomicAdd(&gcur[i], lh[i]);
    __syncthreads();
    for (int i = beg + t; i < end; i += 256) {
        const unsigned p = epk[i - beg];
        const int bkt = p >> 24;
        const int r = atomicAdd(&lcur[bkt], 1);
        pk[lbase[bkt] + r] = p;
    }
}

// ---------- D: per-bucket counting sort -> csr, off, dis ----------
__global__ __launch_bounds__(256) void bsort_kernel(const unsigned* __restrict__ pk,
                                                    const int* __restrict__ bbase,
                                                    int* __restrict__ off,
                                                    float* __restrict__ dis,
                                                    int* __restrict__ csr, int E, int N) {
    __shared__ int ncnt[256], nbs[256], ncur[256];
    __shared__ int wt[4];
    const int t = threadIdx.x;
    const int bkt = blockIdx.x;
    const int gb = bbase[bkt], ge = bbase[bkt + 1];
    ncnt[t] = 0; ncur[t] = 0;
    __syncthreads();
    for (int i = gb + t; i < ge; i += 256)
        atomicAdd(&ncnt[(pk[i] >> 16) & 255], 1);
    __syncthreads();
    const int v = ncnt[t];
    const int lane = t & 63, wid = t >> 6;
    int incl = v;
#pragma unroll
    for (int o = 1; o <= 32; o <<= 1) {
        int u = __shfl_up(incl, o);
        if (lane >= o) incl += u;
    }
    if (lane == 63) wt[wid] = incl;
    __syncthreads();
    int base = 0;
    for (int w = 0; w < wid; ++w) base += wt[w];
    nbs[t] = base + incl - v;
    const int n = bkt * 256 + t;
    if (n < N) {
        off[n] = gb + nbs[t];
        dis[n] = rsqrtf((float)v + 1.0f);
        if (n == N - 1) off[N] = E;
    }
    __syncthreads();
    for (int i = gb + t; i < ge; i += 256) {
        const unsigned p = pk[i];
        const int dl = (p >> 16) & 255;
        const int r = atomicAdd(&ncur[dl], 1);
        csr[gb + nbs[dl] + r] = (int)(p & 0xFFFFu);
    }
}

// ---------- GEMM: LDS-tiled 64x64, bf16 input, emits bf16 h16 + fp8 h8 (layers 1..3) ----------
__global__ __launch_bounds__(256) void gemm64_kernel(const unsigned short* __restrict__ in16,
                                                     const float* __restrict__ W,
                                                     unsigned short* __restrict__ out16,
                                                     unsigned* __restrict__ out8, int N) {
    constexpr int K = 64;
    __shared__ float xs[64][68];
    __shared__ float Wl[64][64];
    const int t = threadIdx.x;
    const int row0 = blockIdx.x * 64;
    const int cq = t & 15, rq = t >> 4;
    float acc[4][4] = {{0.f}};
    {
#pragma unroll
        for (int it = 0; it < 4; ++it) {
            const int idx = it * 256 + t;
            const int r = idx >> 4, c4 = idx & 15;
            const int rr = min(row0 + r, N - 1);
            const ushort4 v = *(const ushort4*)(in16 + (size_t)rr * K + c4 * 4);
            *(float4*)(&xs[r][c4 * 4]) = make_float4(bf2f(v.x), bf2f(v.y), bf2f(v.z), bf2f(v.w));
            *(float4*)(&Wl[r][c4 * 4]) = *(const float4*)(W + (size_t)r * HD + c4 * 4);
        }
        __syncthreads();
#pragma unroll
        for (int k4 = 0; k4 < 16; ++k4) {
            float a[4][4], b[4][4];
#pragma unroll
            for (int i = 0; i < 4; ++i)
                *(float4*)a[i] = *(const float4*)(&xs[rq * 4 + i][k4 * 4]);
#pragma unroll
            for (int kk = 0; kk < 4; ++kk)
                *(float4*)b[kk] = *(const float4*)(&Wl[k4 * 4 + kk][cq * 4]);
#pragma unroll
            for (int kk = 0; kk < 4; ++kk)
#pragma unroll
                for (int i = 0; i < 4; ++i)
#pragma unroll
                    for (int j = 0; j < 4; ++j)
                        acc[i][j] = fmaf(a[i][kk], b[kk][j], acc[i][j]);
        }
    }
#pragma unroll
    for (int i = 0; i < 4; ++i) {
        const int r = row0 + rq * 4 + i;
        if (r < N) {
            ushort4 o;
            o.x = f2bf(acc[i][0]); o.y = f2bf(acc[i][1]);
            o.z = f2bf(acc[i][2]); o.w = f2bf(acc[i][3]);
            *(ushort4*)(out16 + (size_t)r * HD + cq * 4) = o;
            out8[(size_t)r * 16 + cq] = pack_fp8x4(acc[i][0], acc[i][1], acc[i][2], acc[i][3]);
        }
    }
}

// ---------- fused aggregation: 8-edge fp8 gathers, prefetch depth 1, packed-f32 accumulate ----------
// FINAL variant additionally emits u8/d8 (folds the old uprep kernel).
template <bool FINAL>
__global__ __launch_bounds__(256) void agg_kernel(const int* __restrict__ csr,
                                                  const int* __restrict__ off,
                                                  const float* __restrict__ dis,
                                                  const unsigned short* __restrict__ h16,
                                                  const unsigned* __restrict__ h8,
                                                  const float* __restrict__ b,
                                                  unsigned short* __restrict__ z16out,
                                                  const unsigned short* __restrict__ zall,
                                                  const float* __restrict__ Wp,
                                                  unsigned* __restrict__ u8,
                                                  unsigned* __restrict__ d8, int N) {
    const int lane = threadIdx.x & 63;
    const int wid  = threadIdx.x >> 6;
    const int n = blockIdx.x * 4 + wid;
    if (n >= N) return;
    const int beg = off[n];
    const int c = min(off[n + 1] - beg, 64);
    int   s_l = 0;
    float w_l = 0.f;
    if (lane < c) {
        s_l = csr[beg + lane];
        w_l = dis[s_l];
    }
    const float dn = dis[n];
    const int g = lane >> 3;
    const int p = lane & 7;
    floatx2 a01 = {0.f, 0.f}, a23 = {0.f, 0.f}, a45 = {0.f, 0.f}, a67 = {0.f, 0.f};
    // prefetch edge group 0
    int   sE = __shfl(s_l, g);
    float wE = __shfl(w_l, g);
    uint2 hv = *(const uint2*)(h8 + (size_t)sE * 16 + p * 2);
    for (int e = 8; e < c; e += 8) {
        const int   sN = __shfl(s_l, e + g);
        const float wN = __shfl(w_l, e + g);
        const uint2 nv = *(const uint2*)(h8 + (size_t)sN * 16 + p * 2);
        floatx2 wE2; wE2[0] = wE; wE2[1] = wE;
        a01 += __builtin_amdgcn_cvt_pk_f32_fp8(hv.x, false) * wE2;
        a23 += __builtin_amdgcn_cvt_pk_f32_fp8(hv.x, true)  * wE2;
        a45 += __builtin_amdgcn_cvt_pk_f32_fp8(hv.y, false) * wE2;
        a67 += __builtin_amdgcn_cvt_pk_f32_fp8(hv.y, true)  * wE2;
        hv = nv; wE = wN;
    }
    {
        floatx2 wE2; wE2[0] = wE; wE2[1] = wE;
        a01 += __builtin_amdgcn_cvt_pk_f32_fp8(hv.x, false) * wE2;
        a23 += __builtin_amdgcn_cvt_pk_f32_fp8(hv.x, true)  * wE2;
        a45 += __builtin_amdgcn_cvt_pk_f32_fp8(hv.y, false) * wE2;
        a67 += __builtin_amdgcn_cvt_pk_f32_fp8(hv.y, true)  * wE2;
    }
#pragma unroll
    for (int st = 8; st <= 32; st <<= 1) {
        floatx2 t0, t1, t2, t3;
        t0[0] = __shfl_xor(a01[0], st); t0[1] = __shfl_xor(a01[1], st);
        t1[0] = __shfl_xor(a23[0], st); t1[1] = __shfl_xor(a23[1], st);
        t2[0] = __shfl_xor(a45[0], st); t2[1] = __shfl_xor(a45[1], st);
        t3[0] = __shfl_xor(a67[0], st); t3[1] = __shfl_xor(a67[1], st);
        a01 += t0; a23 += t1; a45 += t2; a67 += t3;
    }
    if (g == 0) {
        const uint4 sv = *(const uint4*)(h16 + (size_t)n * HD + p * 8);
        const unsigned ss[4] = {sv.x, sv.y, sv.z, sv.w};
        floatx2 dn2; dn2[0] = dn; dn2[1] = dn;
        floatx2 s01, s23, s45, s67;
        s01[0] = bf2f((unsigned short)(ss[0] & 0xFFFFu)); s01[1] = bf2f((unsigned short)(ss[0] >> 16));
        s23[0] = bf2f((unsigned short)(ss[1] & 0xFFFFu)); s23[1] = bf2f((unsigned short)(ss[1] >> 16));
        s45[0] = bf2f((unsigned short)(ss[2] & 0xFFFFu)); s45[1] = bf2f((unsigned short)(ss[2] >> 16));
        s67[0] = bf2f((unsigned short)(ss[3] & 0xFFFFu)); s67[1] = bf2f((unsigned short)(ss[3] >> 16));
        a01 += s01 * dn2; a23 += s23 * dn2; a45 += s45 * dn2; a67 += s67 * dn2;
        const float4 b0 = *(const float4*)(b + p * 8);
        const float4 b1 = *(const float4*)(b + p * 8 + 4);
        float o[8];
        o[0] = fmaxf(fmaf(a01[0], dn, b0.x), 0.f);
        o[1] = fmaxf(fmaf(a01[1], dn, b0.y), 0.f);
        o[2] = fmaxf(fmaf(a23[0], dn, b0.z), 0.f);
        o[3] = fmaxf(fmaf(a23[1], dn, b0.w), 0.f);
        o[4] = fmaxf(fmaf(a45[0], dn, b1.x), 0.f);
        o[5] = fmaxf(fmaf(a45[1], dn, b1.y), 0.f);
        o[6] = fmaxf(fmaf(a67[0], dn, b1.z), 0.f);
        o[7] = fmaxf(fmaf(a67[1], dn, b1.w), 0.f);
        unsigned short z3b[8];
#pragma unroll
        for (int j = 0; j < 8; ++j) z3b[j] = f2bf(o[j]);
        unsigned short* zp = z16out + (size_t)n * HD + p * 8;
        *(ushort4*)zp = *(ushort4*)z3b;
        *(ushort4*)(zp + 4) = *(ushort4*)(z3b + 4);
        if constexpr (FINAL) {
            // fold uprep: read layers 0..2 (final), layer 3 from z3b (identical bf16 round-trip)
            const size_t NH = (size_t)N_NODES * HD;
            const unsigned short* l0 = zall + 0 * NH + (size_t)n * HD + p * 8;
            const unsigned short* l1 = zall + 1 * NH + (size_t)n * HD + p * 8;
            const unsigned short* l2 = zall + 2 * NH + (size_t)n * HD + p * 8;
            unsigned short L0[8], L1[8], L2[8];
            *(ushort4*)L0 = *(const ushort4*)l0; *(ushort4*)(L0 + 4) = *(const ushort4*)(l0 + 4);
            *(ushort4*)L1 = *(const ushort4*)l1; *(ushort4*)(L1 + 4) = *(const ushort4*)(l1 + 4);
            *(ushort4*)L2 = *(const ushort4*)l2; *(ushort4*)(L2 + 4) = *(const ushort4*)(l2 + 4);
            float wpc[16];
#pragma unroll
            for (int m = 0; m < 16; ++m) wpc[m] = Wp[m];
            unsigned uo[8], dvo[8];
#pragma unroll
            for (int j = 0; j < 8; ++j) {
                const float v0 = bf2f(L0[j]), v1 = bf2f(L1[j]);
                const float v2 = bf2f(L2[j]), v3 = bf2f(z3b[j]);
                dvo[j] = pack_fp8x4(v0, v1, v2, v3);
                const float u0v = v0 * wpc[0] + v1 * wpc[4] + v2 * wpc[8]  + v3 * wpc[12];
                const float u1v = v0 * wpc[1] + v1 * wpc[5] + v2 * wpc[9]  + v3 * wpc[13];
                const float u2v = v0 * wpc[2] + v1 * wpc[6] + v2 * wpc[10] + v3 * wpc[14];
                const float u3v = v0 * wpc[3] + v1 * wpc[7] + v2 * wpc[11] + v3 * wpc[15];
                uo[j] = pack_fp8x4(u0v, u1v, u2v, u3v);
            }
            unsigned* up = u8 + (size_t)n * HD + p * 8;
            unsigned* dp = d8 + (size_t)n * HD + p * 8;
            *(uint4*)up = *(uint4*)uo;  *(uint4*)(up + 4) = *(uint4*)(uo + 4);
            *(uint4*)dp = *(uint4*)dvo; *(uint4*)(dp + 4) = *(uint4*)(dvo + 4);
        }
    }
}

// ---------- link prediction + BCE loss: 16-lane groups, 8 edges / wave-iter ----------
__global__ __launch_bounds__(256) void linkpred_kernel(const unsigned* __restrict__ u8,
                                                       const unsigned* __restrict__ d8,
                                                       const int* __restrict__ pos,
                                                       const int* __restrict__ neg,
                                                       const float* __restrict__ bp,
                                                       double* __restrict__ acc, int EP) {
    const int lane = threadIdx.x & 63;
    const int wid  = threadIdx.x >> 6;
    const int grp  = lane >> 4;
    const int p    = lane & 15;
    const float bpv = bp[0];
    int gw = blockIdx.x * 4 + wid;
    const int nw = gridDim.x * 4;
    const int nchunks = (2 * EP) >> 3;
    float lsum = 0.f;
    for (int c0 = gw; c0 < nchunks; c0 += nw) {
        const int c = __builtin_amdgcn_readfirstlane(c0);
        const int i0 = c << 3;
        const bool is_pos = i0 < EP;
        const int* __restrict__ eptr = is_pos ? pos : neg;
        const int jj0 = is_pos ? i0 : i0 - EP;
        int idx = 0;
        if (lane < 16)
            idx = (lane < 8) ? eptr[jj0 + lane] : eptr[EP + jj0 + lane - 8];
        const int e0a = __shfl(idx, grp),     e1a = __shfl(idx, 8 + grp);
        const int e0b = __shfl(idx, 4 + grp), e1b = __shfl(idx, 12 + grp);
        const uint4 ua = *(const uint4*)(u8 + (size_t)e0a * HD + p * 4);
        const uint4 da = *(const uint4*)(d8 + (size_t)e1a * HD + p * 4);
        const uint4 ub = *(const uint4*)(u8 + (size_t)e0b * HD + p * 4);
        const uint4 db = *(const uint4*)(d8 + (size_t)e1b * HD + p * 4);
        float tA = dot16_fp8(ua, da);
        float tB = dot16_fp8(ub, db);
#pragma unroll
        for (int st = 1; st <= 8; st <<= 1) {
            tA += __shfl_xor(tA, st);
            tB += __shfl_xor(tB, st);
        }
        const float ga = __shfl(tA, (lane & 3) * 16);
        const float gb = __shfl(tB, (lane & 3) * 16);
        const float tt = (lane < 4) ? ga : gb;
        if (lane < 8) {
            float logit  = tt + bpv;
            float target = (i0 + lane == EP) ? 1.f : 0.f;
            lsum += fmaxf(logit, 0.f) - logit * target + log1pf(expf(-fabsf(logit)));
        }
    }
#pragma unroll
    for (int o = 32; o >= 1; o >>= 1) lsum += __shfl_xor(lsum, o);
    __shared__ float wsum[4];
    if (lane == 0) wsum[wid] = lsum;
    __syncthreads();
    if (threadIdx.x == 0) {
        double bs = (double)wsum[0] + (double)wsum[1] + (double)wsum[2] + (double)wsum[3];
        atomicAdd(acc, bs);
    }
}

__global__ void loss_final(const double* __restrict__ acc, float* __restrict__ out, int denom) {
    out[0] = (float)(acc[0] / (double)denom);
}

extern "C" void kernel_launch(void* const* d_in, const int* in_sizes, int n_in,
                              void* d_out, int out_size, void* d_ws, size_t ws_size,
                              hipStream_t stream) {
    const float* x   = (const float*)d_in[0];
    const int*   ei  = (const int*)d_in[1];
    const int*   pos = (const int*)d_in[2];
    const int*   neg = (const int*)d_in[3];
    const float* W0  = (const float*)d_in[4];
    const float* b0  = (const float*)d_in[5];
    const float* Wh  = (const float*)d_in[6];
    const float* bh  = (const float*)d_in[7];
    const float* Wp  = (const float*)d_in[8];
    const float* bp  = (const float*)d_in[9];
    const int E  = in_sizes[1] / 2;   // 800000
    const int EP = in_sizes[2] / 2;   // 100000
    const int N  = N_NODES;
    const size_t NH = (size_t)N * HD;

    // ---- workspace layout (256B aligned) ----
    char* ws = (char*)d_ws;
    size_t off_b = 0;
    auto alloc = [&](size_t bytes) { char* p = ws + off_b; off_b = (off_b + bytes + 255) & ~(size_t)255; return p; };
    unsigned short* h16 = (unsigned short*)alloc(NH * sizeof(unsigned short));       // 6.4 MB
    unsigned*       h8  = (unsigned*)alloc(NH);                                      // 3.2 MB
    unsigned short* z16 = (unsigned short*)alloc(4 * NH * sizeof(unsigned short));   // 25.6 MB
    unsigned*       u8  = (unsigned*)alloc(NH * sizeof(unsigned));                   // 12.8 MB
    unsigned*       d8  = (unsigned*)alloc(NH * sizeof(unsigned));                   // 12.8 MB
    float* dis = (float*)alloc((size_t)N * sizeof(float));                           // 200 KB
    int*   off = (int*)alloc((size_t)(N + 1) * sizeof(int));                         // 200 KB
    int*   csr = (int*)alloc((size_t)E * sizeof(int));                               // 3.2 MB
    unsigned* pk = (unsigned*)alloc((size_t)E * sizeof(unsigned));                   // 3.2 MB
    int*   bbase = (int*)alloc((size_t)(NBKT + 1) * sizeof(int));
    int*   gcur  = (int*)alloc((size_t)NBKT * sizeof(int));
    char*  zbase = ws + off_b;
    int*   bcnt = (int*)alloc((size_t)NBKT * sizeof(int));
    double* acc = (double*)alloc(sizeof(double));
    size_t zero_bytes = (size_t)((char*)acc - zbase) + sizeof(double);

    hipMemsetAsync(zbase, 0, zero_bytes, stream);

    const int* src = ei;
    const int* dst = ei + E;

    const int gemm_blocks = (N + 63) / 64;           // 782
    const int bhist_blocks = (E + 2047) / 2048;      // 391
    const int agg_blocks  = (N + 3) / 4;

    // fused gemm<128> + bhist, then CSR build
    gemm128_bhist_kernel<<<gemm_blocks + bhist_blocks, 256, 0, stream>>>(
        x, W0, h16, h8, dst, bcnt, N, E, gemm_blocks);
    bscan_kernel<<<1, 256, 0, stream>>>(bcnt, bbase, gcur);
    partition_kernel<<<(E + 8191) / 8192, 256, 0, stream>>>(src, dst, gcur, pk, E);
    bsort_kernel<<<NBKT, 256, 0, stream>>>(pk, bbase, off, dis, csr, E, N);

    // layer 0 aggregation
    agg_kernel<false><<<agg_blocks, 256, 0, stream>>>(csr, off, dis, h16, h8, b0,
                                                      z16, z16, Wp, u8, d8, N);

    // layers 1..3 (layer 3 agg folds uprep)
    for (int l = 1; l < 4; ++l) {
        unsigned short* zprev = z16 + (size_t)(l - 1) * NH;
        unsigned short* zcur  = z16 + (size_t)l * NH;
        gemm64_kernel<<<gemm_blocks, 256, 0, stream>>>(zprev, Wh + (size_t)(l - 1) * HD * HD, h16, h8, N);
        if (l < 3) {
            agg_kernel<false><<<agg_blocks, 256, 0, stream>>>(csr, off, dis, h16, h8,
                                                              bh + (size_t)(l - 1) * HD,
                                                              zcur, z16, Wp, u8, d8, N);
        } else {
            agg_kernel<true><<<agg_blocks, 256, 0, stream>>>(csr, off, dis, h16, h8,
                                                             bh + (size_t)(l - 1) * HD,
                                                             zcur, z16, Wp, u8, d8, N);
        }
    }

    // link prediction + loss
    linkpred_kernel<<<2048, 256, 0, stream>>>(u8, d8, pos, neg, bp, acc, EP);
    loss_final<<<1, 1, 0, stream>>>(acc, (float*)d_out, 2 * EP);
}

// Round 21
// 274.449 us; speedup vs baseline: 1.0458x; 1.0056x over previous
//
#include <hip/hip_runtime.h>
#include <hip/hip_bf16.h>
#include <math.h>

constexpr int N_NODES = 50000;
constexpr int HD = 64;
constexpr int NBKT = (N_NODES + 255) / 256;   // 196 buckets of 256 nodes

typedef float floatx2 __attribute__((ext_vector_type(2)));

__device__ __forceinline__ float bf2f(unsigned short u) {
    return __uint_as_float((unsigned)u << 16);
}
__device__ __forceinline__ unsigned short f2bf(float f) {
    __hip_bfloat16 b = __float2bfloat16(f);
    return *(unsigned short*)&b;
}
__device__ __forceinline__ unsigned pack_fp8x4(float a, float b, float c, float d) {
    unsigned p = __builtin_amdgcn_cvt_pk_fp8_f32(a, b, 0u, false);
    return __builtin_amdgcn_cvt_pk_fp8_f32(c, d, p, true);
}
// dot of 16 fp8 pairs held in two uint4s
__device__ __forceinline__ float dot16_fp8(uint4 u, uint4 d) {
    const unsigned uu[4] = {u.x, u.y, u.z, u.w};
    const unsigned dd[4] = {d.x, d.y, d.z, d.w};
    float s = 0.f;
#pragma unroll
    for (int q = 0; q < 4; ++q) {
        floatx2 ua = __builtin_amdgcn_cvt_pk_f32_fp8(uu[q], false);
        floatx2 ub = __builtin_amdgcn_cvt_pk_f32_fp8(uu[q], true);
        floatx2 da = __builtin_amdgcn_cvt_pk_f32_fp8(dd[q], false);
        floatx2 db = __builtin_amdgcn_cvt_pk_f32_fp8(dd[q], true);
        s = fmaf(ua[0], da[0], s);
        s = fmaf(ua[1], da[1], s);
        s = fmaf(ub[0], db[0], s);
        s = fmaf(ub[1], db[1], s);
    }
    return s;
}

// ---------- fused: gemm<128> (blocks < nGemm) + bucket histogram (blocks >= nGemm) ----------
__global__ __launch_bounds__(256) void gemm128_bhist_kernel(
        const float* __restrict__ in_, const float* __restrict__ W,
        unsigned short* __restrict__ out16, unsigned* __restrict__ out8,
        const int* __restrict__ dst, int* __restrict__ bcnt,
        int N, int E, int nGemm) {
    __shared__ float xs[64][68];
    __shared__ float Wl[64][64];
    const int t = threadIdx.x;
    if ((int)blockIdx.x >= nGemm) {
        // --- bhist path (LDS aliased onto xs) ---
        int* lh = (int*)&xs[0][0];
        lh[t] = 0;
        __syncthreads();
        const int beg = ((int)blockIdx.x - nGemm) * 2048;
        const int end = min(beg + 2048, E);
        for (int i = beg + t; i < end; i += 256)
            atomicAdd(&lh[dst[i] >> 8], 1);
        __syncthreads();
        if (t < NBKT && lh[t]) atomicAdd(&bcnt[t], lh[t]);
        return;
    }
    // --- gemm path, K=128, fp32 input ---
    constexpr int K = 128;
    const int row0 = blockIdx.x * 64;
    const int cq = t & 15, rq = t >> 4;
    float acc[4][4] = {{0.f}};
    for (int kc = 0; kc < K; kc += 64) {
#pragma unroll
        for (int it = 0; it < 4; ++it) {
            const int idx = it * 256 + t;
            const int r = idx >> 4, c4 = idx & 15;
            const int rr = min(row0 + r, N - 1);
            *(float4*)(&xs[r][c4 * 4]) = *(const float4*)(in_ + (size_t)rr * K + kc + c4 * 4);
            *(float4*)(&Wl[r][c4 * 4]) = *(const float4*)(W + (size_t)(kc + r) * HD + c4 * 4);
        }
        __syncthreads();
#pragma unroll
        for (int k4 = 0; k4 < 16; ++k4) {
            float a[4][4], b[4][4];
#pragma unroll
            for (int i = 0; i < 4; ++i)
                *(float4*)a[i] = *(const float4*)(&xs[rq * 4 + i][k4 * 4]);
#pragma unroll
            for (int kk = 0; kk < 4; ++kk)
                *(float4*)b[kk] = *(const float4*)(&Wl[k4 * 4 + kk][cq * 4]);
#pragma unroll
            for (int kk = 0; kk < 4; ++kk)
#pragma unroll
                for (int i = 0; i < 4; ++i)
#pragma unroll
                    for (int j = 0; j < 4; ++j)
                        acc[i][j] = fmaf(a[i][kk], b[kk][j], acc[i][j]);
        }
        __syncthreads();
    }
#pragma unroll
    for (int i = 0; i < 4; ++i) {
        const int r = row0 + rq * 4 + i;
        if (r < N) {
            ushort4 o;
            o.x = f2bf(acc[i][0]); o.y = f2bf(acc[i][1]);
            o.z = f2bf(acc[i][2]); o.w = f2bf(acc[i][3]);
            *(ushort4*)(out16 + (size_t)r * HD + cq * 4) = o;
            out8[(size_t)r * 16 + cq] = pack_fp8x4(acc[i][0], acc[i][1], acc[i][2], acc[i][3]);
        }
    }
}

// ---------- B: scan bucket counts -> bbase, init gcur ----------
__global__ __launch_bounds__(256) void bscan_kernel(const int* __restrict__ bcnt,
                                                    int* __restrict__ bbase,
                                                    int* __restrict__ gcur) {
    const int t = threadIdx.x;
    const int v = (t < NBKT) ? bcnt[t] : 0;
    const int lane = t & 63, wid = t >> 6;
    int incl = v;
#pragma unroll
    for (int o = 1; o <= 32; o <<= 1) {
        int u = __shfl_up(incl, o);
        if (lane >= o) incl += u;
    }
    __shared__ int wt[4];
    if (lane == 63) wt[wid] = incl;
    __syncthreads();
    int base = 0;
    for (int w = 0; w < wid; ++w) base += wt[w];
    const int excl = base + incl - v;
    if (t < NBKT) { bbase[t] = excl; gcur[t] = excl; }
    if (t == NBKT - 1) bbase[NBKT] = excl + v;
}

// ---------- C: partition edges into bucket-grouped pk ----------
__global__ __launch_bounds__(256) void partition_kernel(const int* __restrict__ src,
                                                        const int* __restrict__ dst,
                                                        int* __restrict__ gcur,
                                                        unsigned* __restrict__ pk, int E) {
    __shared__ unsigned epk[8192];
    __shared__ int lh[NBKT], lbase[NBKT], lcur[NBKT];
    const int t = threadIdx.x;
    for (int i = t; i < NBKT; i += 256) { lh[i] = 0; lcur[i] = 0; }
    __syncthreads();
    const int beg = blockIdx.x * 8192;
    const int end = min(beg + 8192, E);
    for (int i = beg + t; i < end; i += 256) {
        const int s = src[i], d = dst[i];
        const int bkt = d >> 8;
        epk[i - beg] = ((unsigned)bkt << 24) | ((unsigned)(d & 255) << 16) | (unsigned)s;
        atomicAdd(&lh[bkt], 1);
    }
    __syncthreads();
    for (int i = t; i < NBKT; i += 256)
        if (lh[i]) lbase[i] = atomicAdd(&gcur[i], lh[i]);
    __syncthreads();
    for (int i = beg + t; i < end; i += 256) {
        const unsigned p = epk[i - beg];
        const int bkt = p >> 24;
        const int r = atomicAdd(&lcur[bkt], 1);
        pk[lbase[bkt] + r] = p;
    }
}

// ---------- D: per-bucket counting sort -> csr, off, dis ----------
__global__ __launch_bounds__(256) void bsort_kernel(const unsigned* __restrict__ pk,
                                                    const int* __restrict__ bbase,
                                                    int* __restrict__ off,
                                                    float* __restrict__ dis,
                                                    int* __restrict__ csr, int E, int N) {
    __shared__ int ncnt[256], nbs[256], ncur[256];
    __shared__ int wt[4];
    const int t = threadIdx.x;
    const int bkt = blockIdx.x;
    const int gb = bbase[bkt], ge = bbase[bkt + 1];
    ncnt[t] = 0; ncur[t] = 0;
    __syncthreads();
    for (int i = gb + t; i < ge; i += 256)
        atomicAdd(&ncnt[(pk[i] >> 16) & 255], 1);
    __syncthreads();
    const int v = ncnt[t];
    const int lane = t & 63, wid = t >> 6;
    int incl = v;
#pragma unroll
    for (int o = 1; o <= 32; o <<= 1) {
        int u = __shfl_up(incl, o);
        if (lane >= o) incl += u;
    }
    if (lane == 63) wt[wid] = incl;
    __syncthreads();
    int base = 0;
    for (int w = 0; w < wid; ++w) base += wt[w];
    nbs[t] = base + incl - v;
    const int n = bkt * 256 + t;
    if (n < N) {
        off[n] = gb + nbs[t];
        dis[n] = rsqrtf((float)v + 1.0f);
        if (n == N - 1) off[N] = E;
    }
    __syncthreads();
    for (int i = gb + t; i < ge; i += 256) {
        const unsigned p = pk[i];
        const int dl = (p >> 16) & 255;
        const int r = atomicAdd(&ncur[dl], 1);
        csr[gb + nbs[dl] + r] = (int)(p & 0xFFFFu);
    }
}

// ---------- GEMM: LDS-tiled 64x64, bf16 input, emits bf16 h16 + fp8 h8 (layers 1..3) ----------
__global__ __launch_bounds__(256) void gemm64_kernel(const unsigned short* __restrict__ in16,
                                                     const float* __restrict__ W,
                                                     unsigned short* __restrict__ out16,
                                                     unsigned* __restrict__ out8, int N) {
    constexpr int K = 64;
    __shared__ float xs[64][68];
    __shared__ float Wl[64][64];
    const int t = threadIdx.x;
    const int row0 = blockIdx.x * 64;
    const int cq = t & 15, rq = t >> 4;
    float acc[4][4] = {{0.f}};
    {
#pragma unroll
        for (int it = 0; it < 4; ++it) {
            const int idx = it * 256 + t;
            const int r = idx >> 4, c4 = idx & 15;
            const int rr = min(row0 + r, N - 1);
            const ushort4 v = *(const ushort4*)(in16 + (size_t)rr * K + c4 * 4);
            *(float4*)(&xs[r][c4 * 4]) = make_float4(bf2f(v.x), bf2f(v.y), bf2f(v.z), bf2f(v.w));
            *(float4*)(&Wl[r][c4 * 4]) = *(const float4*)(W + (size_t)r * HD + c4 * 4);
        }
        __syncthreads();
#pragma unroll
        for (int k4 = 0; k4 < 16; ++k4) {
            float a[4][4], b[4][4];
#pragma unroll
            for (int i = 0; i < 4; ++i)
                *(float4*)a[i] = *(const float4*)(&xs[rq * 4 + i][k4 * 4]);
#pragma unroll
            for (int kk = 0; kk < 4; ++kk)
                *(float4*)b[kk] = *(const float4*)(&Wl[k4 * 4 + kk][cq * 4]);
#pragma unroll
            for (int kk = 0; kk < 4; ++kk)
#pragma unroll
                for (int i = 0; i < 4; ++i)
#pragma unroll
                    for (int j = 0; j < 4; ++j)
                        acc[i][j] = fmaf(a[i][kk], b[kk][j], acc[i][j]);
        }
    }
#pragma unroll
    for (int i = 0; i < 4; ++i) {
        const int r = row0 + rq * 4 + i;
        if (r < N) {
            ushort4 o;
            o.x = f2bf(acc[i][0]); o.y = f2bf(acc[i][1]);
            o.z = f2bf(acc[i][2]); o.w = f2bf(acc[i][3]);
            *(ushort4*)(out16 + (size_t)r * HD + cq * 4) = o;
            out8[(size_t)r * 16 + cq] = pack_fp8x4(acc[i][0], acc[i][1], acc[i][2], acc[i][3]);
        }
    }
}

// ---------- fused aggregation: 8-edge fp8 gathers, prefetch depth 1 ----------
// FINAL variant additionally emits u8/d8 (folds the old uprep kernel).
template <bool FINAL>
__global__ __launch_bounds__(256) void agg_kernel(const int* __restrict__ csr,
                                                  const int* __restrict__ off,
                                                  const float* __restrict__ dis,
                                                  const unsigned short* __restrict__ h16,
                                                  const unsigned* __restrict__ h8,
                                                  const float* __restrict__ b,
                                                  unsigned short* __restrict__ z16out,
                                                  const unsigned short* __restrict__ zall,
                                                  const float* __restrict__ Wp,
                                                  unsigned* __restrict__ u8,
                                                  unsigned* __restrict__ d8, int N) {
    const int lane = threadIdx.x & 63;
    const int wid  = threadIdx.x >> 6;
    const int n = blockIdx.x * 4 + wid;
    if (n >= N) return;
    const int beg = off[n];
    const int c = min(off[n + 1] - beg, 64);
    int   s_l = 0;
    float w_l = 0.f;
    if (lane < c) {
        s_l = csr[beg + lane];
        w_l = dis[s_l];
    }
    const float dn = dis[n];
    const int g = lane >> 3;
    const int p = lane & 7;
    float a[8];
#pragma unroll
    for (int j = 0; j < 8; ++j) a[j] = 0.f;
    // prefetch edge group 0
    int   sE = __shfl(s_l, g);
    float wE = __shfl(w_l, g);
    uint2 hv = *(const uint2*)(h8 + (size_t)sE * 16 + p * 2);
    for (int e = 8; e < c; e += 8) {
        const int   sN = __shfl(s_l, e + g);
        const float wN = __shfl(w_l, e + g);
        const uint2 nv = *(const uint2*)(h8 + (size_t)sN * 16 + p * 2);
        floatx2 f01 = __builtin_amdgcn_cvt_pk_f32_fp8(hv.x, false);
        floatx2 f23 = __builtin_amdgcn_cvt_pk_f32_fp8(hv.x, true);
        floatx2 f45 = __builtin_amdgcn_cvt_pk_f32_fp8(hv.y, false);
        floatx2 f67 = __builtin_amdgcn_cvt_pk_f32_fp8(hv.y, true);
        a[0] = fmaf(f01[0], wE, a[0]); a[1] = fmaf(f01[1], wE, a[1]);
        a[2] = fmaf(f23[0], wE, a[2]); a[3] = fmaf(f23[1], wE, a[3]);
        a[4] = fmaf(f45[0], wE, a[4]); a[5] = fmaf(f45[1], wE, a[5]);
        a[6] = fmaf(f67[0], wE, a[6]); a[7] = fmaf(f67[1], wE, a[7]);
        hv = nv; wE = wN;
    }
    {
        floatx2 f01 = __builtin_amdgcn_cvt_pk_f32_fp8(hv.x, false);
        floatx2 f23 = __builtin_amdgcn_cvt_pk_f32_fp8(hv.x, true);
        floatx2 f45 = __builtin_amdgcn_cvt_pk_f32_fp8(hv.y, false);
        floatx2 f67 = __builtin_amdgcn_cvt_pk_f32_fp8(hv.y, true);
        a[0] = fmaf(f01[0], wE, a[0]); a[1] = fmaf(f01[1], wE, a[1]);
        a[2] = fmaf(f23[0], wE, a[2]); a[3] = fmaf(f23[1], wE, a[3]);
        a[4] = fmaf(f45[0], wE, a[4]); a[5] = fmaf(f45[1], wE, a[5]);
        a[6] = fmaf(f67[0], wE, a[6]); a[7] = fmaf(f67[1], wE, a[7]);
    }
#pragma unroll
    for (int st = 8; st <= 32; st <<= 1)
#pragma unroll
        for (int j = 0; j < 8; ++j) a[j] += __shfl_xor(a[j], st);
    if (g == 0) {
        const uint4 sv = *(const uint4*)(h16 + (size_t)n * HD + p * 8);
        const unsigned ss[4] = {sv.x, sv.y, sv.z, sv.w};
        const float4 b0 = *(const float4*)(b + p * 8);
        const float4 b1 = *(const float4*)(b + p * 8 + 4);
        const float bb[8] = {b0.x, b0.y, b0.z, b0.w, b1.x, b1.y, b1.z, b1.w};
        float o[8];
#pragma unroll
        for (int q = 0; q < 4; ++q) {
            o[2 * q]     = a[2 * q]     + __uint_as_float(ss[q] << 16) * dn;
            o[2 * q + 1] = a[2 * q + 1] + __uint_as_float(ss[q] & 0xFFFF0000u) * dn;
        }
        unsigned short z3b[8];
#pragma unroll
        for (int j = 0; j < 8; ++j) {
            const float v = fmaxf(fmaf(o[j], dn, bb[j]), 0.f);
            z3b[j] = f2bf(v);
        }
        unsigned short* zp = z16out + (size_t)n * HD + p * 8;
        *(ushort4*)zp = *(ushort4*)z3b;
        *(ushort4*)(zp + 4) = *(ushort4*)(z3b + 4);
        if constexpr (FINAL) {
            // fold uprep: read layers 0..2 (final), layer 3 from z3b (identical bf16 round-trip)
            const size_t NH = (size_t)N_NODES * HD;
            const unsigned short* l0 = zall + 0 * NH + (size_t)n * HD + p * 8;
            const unsigned short* l1 = zall + 1 * NH + (size_t)n * HD + p * 8;
            const unsigned short* l2 = zall + 2 * NH + (size_t)n * HD + p * 8;
            unsigned short L0[8], L1[8], L2[8];
            *(ushort4*)L0 = *(const ushort4*)l0; *(ushort4*)(L0 + 4) = *(const ushort4*)(l0 + 4);
            *(ushort4*)L1 = *(const ushort4*)l1; *(ushort4*)(L1 + 4) = *(const ushort4*)(l1 + 4);
            *(ushort4*)L2 = *(const ushort4*)l2; *(ushort4*)(L2 + 4) = *(const ushort4*)(l2 + 4);
            float wpc[16];
#pragma unroll
            for (int m = 0; m < 16; ++m) wpc[m] = Wp[m];
            unsigned uo[8], dvo[8];
#pragma unroll
            for (int j = 0; j < 8; ++j) {
                const float v0 = bf2f(L0[j]), v1 = bf2f(L1[j]);
                const float v2 = bf2f(L2[j]), v3 = bf2f(z3b[j]);
                dvo[j] = pack_fp8x4(v0, v1, v2, v3);
                const float u0v = v0 * wpc[0] + v1 * wpc[4] + v2 * wpc[8]  + v3 * wpc[12];
                const float u1v = v0 * wpc[1] + v1 * wpc[5] + v2 * wpc[9]  + v3 * wpc[13];
                const float u2v = v0 * wpc[2] + v1 * wpc[6] + v2 * wpc[10] + v3 * wpc[14];
                const float u3v = v0 * wpc[3] + v1 * wpc[7] + v2 * wpc[11] + v3 * wpc[15];
                uo[j] = pack_fp8x4(u0v, u1v, u2v, u3v);
            }
            unsigned* up = u8 + (size_t)n * HD + p * 8;
            unsigned* dp = d8 + (size_t)n * HD + p * 8;
            *(uint4*)up = *(uint4*)uo;  *(uint4*)(up + 4) = *(uint4*)(uo + 4);
            *(uint4*)dp = *(uint4*)dvo; *(uint4*)(dp + 4) = *(uint4*)(dvo + 4);
        }
    }
}

// ---------- link prediction + BCE loss: 16-lane groups, 8 edges / wave-iter ----------
__global__ __launch_bounds__(256) void linkpred_kernel(const unsigned* __restrict__ u8,
                                                       const unsigned* __restrict__ d8,
                                                       const int* __restrict__ pos,
                                                       const int* __restrict__ neg,
                                                       const float* __restrict__ bp,
                                                       double* __restrict__ acc, int EP) {
    const int lane = threadIdx.x & 63;
    const int wid  = threadIdx.x >> 6;
    const int grp  = lane >> 4;
    const int p    = lane & 15;
    const float bpv = bp[0];
    int gw = blockIdx.x * 4 + wid;
    const int nw = gridDim.x * 4;
    const int nchunks = (2 * EP) >> 3;
    float lsum = 0.f;
    for (int c0 = gw; c0 < nchunks; c0 += nw) {
        const int c = __builtin_amdgcn_readfirstlane(c0);
        const int i0 = c << 3;
        const bool is_pos = i0 < EP;
        const int* __restrict__ eptr = is_pos ? pos : neg;
        const int jj0 = is_pos ? i0 : i0 - EP;
        int idx = 0;
        if (lane < 16)
            idx = (lane < 8) ? eptr[jj0 + lane] : eptr[EP + jj0 + lane - 8];
        const int e0a = __shfl(idx, grp),     e1a = __shfl(idx, 8 + grp);
        const int e0b = __shfl(idx, 4 + grp), e1b = __shfl(idx, 12 + grp);
        const uint4 ua = *(const uint4*)(u8 + (size_t)e0a * HD + p * 4);
        const uint4 da = *(const uint4*)(d8 + (size_t)e1a * HD + p * 4);
        const uint4 ub = *(const uint4*)(u8 + (size_t)e0b * HD + p * 4);
        const uint4 db = *(const uint4*)(d8 + (size_t)e1b * HD + p * 4);
        float tA = dot16_fp8(ua, da);
        float tB = dot16_fp8(ub, db);
#pragma unroll
        for (int st = 1; st <= 8; st <<= 1) {
            tA += __shfl_xor(tA, st);
            tB += __shfl_xor(tB, st);
        }
        const float ga = __shfl(tA, (lane & 3) * 16);
        const float gb = __shfl(tB, (lane & 3) * 16);
        const float tt = (lane < 4) ? ga : gb;
        if (lane < 8) {
            float logit  = tt + bpv;
            float target = (i0 + lane == EP) ? 1.f : 0.f;
            lsum += fmaxf(logit, 0.f) - logit * target + log1pf(expf(-fabsf(logit)));
        }
    }
#pragma unroll
    for (int o = 32; o >= 1; o >>= 1) lsum += __shfl_xor(lsum, o);
    __shared__ float wsum[4];
    if (lane == 0) wsum[wid] = lsum;
    __syncthreads();
    if (threadIdx.x == 0) {
        double bs = (double)wsum[0] + (double)wsum[1] + (double)wsum[2] + (double)wsum[3];
        atomicAdd(acc, bs);
    }
}

__global__ void loss_final(const double* __restrict__ acc, float* __restrict__ out, int denom) {
    out[0] = (float)(acc[0] / (double)denom);
}

extern "C" void kernel_launch(void* const* d_in, const int* in_sizes, int n_in,
                              void* d_out, int out_size, void* d_ws, size_t ws_size,
                              hipStream_t stream) {
    const float* x   = (const float*)d_in[0];
    const int*   ei  = (const int*)d_in[1];
    const int*   pos = (const int*)d_in[2];
    const int*   neg = (const int*)d_in[3];
    const float* W0  = (const float*)d_in[4];
    const float* b0  = (const float*)d_in[5];
    const float* Wh  = (const float*)d_in[6];
    const float* bh  = (const float*)d_in[7];
    const float* Wp  = (const float*)d_in[8];
    const float* bp  = (const float*)d_in[9];
    const int E  = in_sizes[1] / 2;   // 800000
    const int EP = in_sizes[2] / 2;   // 100000
    const int N  = N_NODES;
    const size_t NH = (size_t)N * HD;

    // ---- workspace layout (256B aligned) ----
    char* ws = (char*)d_ws;
    size_t off_b = 0;
    auto alloc = [&](size_t bytes) { char* p = ws + off_b; off_b = (off_b + bytes + 255) & ~(size_t)255; return p; };
    unsigned short* h16 = (unsigned short*)alloc(NH * sizeof(unsigned short));       // 6.4 MB
    unsigned*       h8  = (unsigned*)alloc(NH);                                      // 3.2 MB
    unsigned short* z16 = (unsigned short*)alloc(4 * NH * sizeof(unsigned short));   // 25.6 MB
    unsigned*       u8  = (unsigned*)alloc(NH * sizeof(unsigned));                   // 12.8 MB
    unsigned*       d8  = (unsigned*)alloc(NH * sizeof(unsigned));                   // 12.8 MB
    float* dis = (float*)alloc((size_t)N * sizeof(float));                           // 200 KB
    int*   off = (int*)alloc((size_t)(N + 1) * sizeof(int));                         // 200 KB
    int*   csr = (int*)alloc((size_t)E * sizeof(int));                               // 3.2 MB
    unsigned* pk = (unsigned*)alloc((size_t)E * sizeof(unsigned));                   // 3.2 MB
    int*   bbase = (int*)alloc((size_t)(NBKT + 1) * sizeof(int));
    int*   gcur  = (int*)alloc((size_t)NBKT * sizeof(int));
    char*  zbase = ws + off_b;
    int*   bcnt = (int*)alloc((size_t)NBKT * sizeof(int));
    double* acc = (double*)alloc(sizeof(double));
    size_t zero_bytes = (size_t)((char*)acc - zbase) + sizeof(double);

    hipMemsetAsync(zbase, 0, zero_bytes, stream);

    const int* src = ei;
    const int* dst = ei + E;

    const int gemm_blocks = (N + 63) / 64;           // 782
    const int bhist_blocks = (E + 2047) / 2048;      // 391
    const int agg_blocks  = (N + 3) / 4;

    // fused gemm<128> + bhist, then CSR build
    gemm128_bhist_kernel<<<gemm_blocks + bhist_blocks, 256, 0, stream>>>(
        x, W0, h16, h8, dst, bcnt, N, E, gemm_blocks);
    bscan_kernel<<<1, 256, 0, stream>>>(bcnt, bbase, gcur);
    partition_kernel<<<(E + 8191) / 8192, 256, 0, stream>>>(src, dst, gcur, pk, E);
    bsort_kernel<<<NBKT, 256, 0, stream>>>(pk, bbase, off, dis, csr, E, N);

    // layer 0 aggregation
    agg_kernel<false><<<agg_blocks, 256, 0, stream>>>(csr, off, dis, h16, h8, b0,
                                                      z16, z16, Wp, u8, d8, N);

    // layers 1..3 (layer 3 agg folds uprep)
    for (int l = 1; l < 4; ++l) {
        unsigned short* zprev = z16 + (size_t)(l - 1) * NH;
        unsigned short* zcur  = z16 + (size_t)l * NH;
        gemm64_kernel<<<gemm_blocks, 256, 0, stream>>>(zprev, Wh + (size_t)(l - 1) * HD * HD, h16, h8, N);
        if (l < 3) {
            agg_kernel<false><<<agg_blocks, 256, 0, stream>>>(csr, off, dis, h16, h8,
                                                              bh + (size_t)(l - 1) * HD,
                                                              zcur, z16, Wp, u8, d8, N);
        } else {
            agg_kernel<true><<<agg_blocks, 256, 0, stream>>>(csr, off, dis, h16, h8,
                                                             bh + (size_t)(l - 1) * HD,
                                                             zcur, z16, Wp, u8, d8, N);
        }
    }

    // link prediction + loss
    linkpred_kernel<<<2048, 256, 0, stream>>>(u8, d8, pos, neg, bp, acc, EP);
    loss_final<<<1, 1, 0, stream>>>(acc, (float*)d_out, 2 * EP);
}